// Round 5
// baseline (433.942 us; speedup 1.0000x reference)
//
#include <hip/hip_runtime.h>

// Problem constants
#define B_SZ   64
#define N_IN   1024
#define D_IN   512
#define NC     32
#define DC     64

typedef unsigned short u16;
typedef unsigned int   u32;
typedef __bf16 bf16x8 __attribute__((ext_vector_type(8)));
typedef _Float16 f16x8 __attribute__((ext_vector_type(8)));
typedef unsigned short u16x8 __attribute__((ext_vector_type(8)));
typedef float f32x4  __attribute__((ext_vector_type(4)));
typedef float f32x16 __attribute__((ext_vector_type(16)));

__device__ __forceinline__ float bf2f(u16 u) {
    unsigned x = ((unsigned)u) << 16;
    return __builtin_bit_cast(float, x);
}
__device__ __forceinline__ u16 f2bf(float f) {
    unsigned x = __builtin_bit_cast(unsigned, f);
    unsigned r = (x + 0x7fffu + ((x >> 16) & 1u)) >> 16;   // RNE
    return (u16)r;
}
__device__ __forceinline__ u16 f2h(float f) {             // fp32 -> fp16 bits (RNE)
    return __builtin_bit_cast(u16, (_Float16)f);
}
__device__ __forceinline__ float h2f(u16 h) {
    return (float)__builtin_bit_cast(_Float16, h);
}

#define ASYNC_LDS16(g, l) __builtin_amdgcn_global_load_lds( \
    (const __attribute__((address_space(1))) void*)(g),     \
    (__attribute__((address_space(3))) void*)(l), 16, 0, 0)

// ---------------------------------------------------------------------------
// conv_all: blocks 0..1023 (64 rows each): Ab = bf16(A), Arowp[b][32][512]
// partial row-sums (slot = subblock*2 + row-parity, no atomics, no memset).
// blocks 1024..1087: Wb = bf16(W) (folded former w_conv).
// ---------------------------------------------------------------------------
__global__ __launch_bounds__(256) void conv_all(const float* __restrict__ A,
                                                const float* __restrict__ W,
                                                u16* __restrict__ Ab,
                                                u16* __restrict__ Wb,
                                                float* __restrict__ Arowp) {
    const int tid = threadIdx.x;
    if (blockIdx.x >= 1024) {                 // W -> bf16, 64 blocks
        const int wb = blockIdx.x - 1024;
#pragma unroll
        for (int it = 0; it < 16; ++it) {
            int i = wb * 4096 + it * 256 + tid;
            float4 v = ((const float4*)W)[i];
            uint2 pk;
            pk.x = (u32)f2bf(v.x) | ((u32)f2bf(v.y) << 16);
            pk.y = (u32)f2bf(v.z) | ((u32)f2bf(v.w) << 16);
            ((uint2*)Wb)[i] = pk;
        }
        return;
    }
    const int b  = blockIdx.x >> 4;
    const int r0 = (blockIdx.x & 15) << 6;    // 64 rows per block
    const int q  = tid & 127;                 // float4 slot within row
    const int rh = tid >> 7;                  // row parity
    const size_t rowbase = (size_t)(b * N_IN + r0);
    float a0 = 0.f, a1 = 0.f, a2 = 0.f, a3 = 0.f;
    for (int r = rh; r < 64; r += 2) {
        float4 v = *(const float4*)(A + (rowbase + r) * 512 + q * 4);
        a0 += v.x; a1 += v.y; a2 += v.z; a3 += v.w;
        uint2 pk;
        pk.x = (u32)f2bf(v.x) | ((u32)f2bf(v.y) << 16);
        pk.y = (u32)f2bf(v.z) | ((u32)f2bf(v.w) << 16);
        *(uint2*)(Ab + (rowbase + r) * 512 + q * 4) = pk;
    }
    const int slot = (blockIdx.x & 15) * 2 + rh;      // 0..31
    float* ar = Arowp + ((size_t)b * 32 + slot) * 512 + q * 4;
    ar[0] = a0; ar[1] = a1; ar[2] = a2; ar[3] = a3;
}

// ---------------------------------------------------------------------------
// s0_squash: s[b][z] = (1/32) Arow[b].Wb[:,z]; squash; -> outs
// grid (8 z-tiles, 32 b-pairs) = 256 blocks (full GPU).
// ---------------------------------------------------------------------------
__global__ __launch_bounds__(256) void s0_squash(const float* __restrict__ Arowp,
                                                 const u16* __restrict__ Wb,
                                                 float* __restrict__ outs) {
    __shared__ float Al[2 * 512];
    const int tid = threadIdx.x;
    const int z   = blockIdx.x * 256 + tid;
    const int bg  = blockIdx.y * 2;

    for (int t = tid; t < 1024; t += 256) {   // reduce 32 partial slots
        int bb = t >> 9, k = t & 511;
        const float* p = Arowp + ((size_t)(bg + bb) * 32) * 512 + k;
        float s = 0.f;
#pragma unroll
        for (int j = 0; j < 32; ++j) s += p[(size_t)j * 512];
        Al[t] = s;
    }
    __syncthreads();

    float acc[2] = {};
    for (int k = 0; k < 512; ++k) {
        float wv = bf2f(Wb[(size_t)k * 2048 + z]);
        acc[0] += Al[k] * wv;                 // LDS broadcast
        acc[1] += Al[512 + k] * wv;
    }
#pragma unroll
    for (int bb = 0; bb < 2; ++bb) {
        float v = acc[bb] * 0.03125f;
        float sq = v * v;
        for (int off = 32; off; off >>= 1) sq += __shfl_xor(sq, off);
        outs[(size_t)(bg + bb) * 2048 + z] = v * (1.0f / sqrtf(sq + 1e-7f));
    }
}

// ---------------------------------------------------------------------------
// g_pack: Gpack[b][kk][n][kq] = bf16( sum_d Wb[kk*32+kq][n*64+d] * outs[b][n*64+d] )
// Vectorized: u16x8 W loads (broadcast), f32x4 LDS reads (pad 132).
// grid (32 k-tiles of 16, 16 n-pairs).
// ---------------------------------------------------------------------------
__global__ __launch_bounds__(256) void g_pack(const u16* __restrict__ Wb,
                                              const float* __restrict__ outs,
                                              u16* __restrict__ Gpack) {
    __shared__ float vl[64 * 132];          // [b][2n x 64d], pad->132 (16B align)
    const int tid = threadIdx.x;
    const int kt  = blockIdx.x;
    const int np  = blockIdx.y;

    for (int t = tid; t < 8192; t += 256) {
        int b = t >> 7, idx = t & 127;
        vl[b * 132 + idx] = outs[(size_t)b * 2048 + np * 128 + idx];
    }
    __syncthreads();

    const int bs = tid & 15;
    const int k  = kt * 16 + (tid >> 4);
    float acc[4][2] = {};
#pragma unroll
    for (int n2 = 0; n2 < 2; ++n2) {
        const u16* wr = Wb + (size_t)k * 2048 + (np * 2 + n2) * 64;
#pragma unroll
        for (int d8 = 0; d8 < 8; ++d8) {
            u16x8 w8 = *(const u16x8*)&wr[d8 * 8];     // 16 lanes share addr
            float wf[8];
#pragma unroll
            for (int j = 0; j < 8; ++j) wf[j] = bf2f(w8[j]);
#pragma unroll
            for (int bb = 0; bb < 4; ++bb) {
                const float* vp = &vl[(bs + 16 * bb) * 132 + n2 * 64 + d8 * 8];
                f32x4 va = *(const f32x4*)vp;
                f32x4 vb = *(const f32x4*)(vp + 4);
#pragma unroll
                for (int j = 0; j < 4; ++j) {
                    acc[bb][n2] += wf[j]     * va[j];
                    acc[bb][n2] += wf[j + 4] * vb[j];
                }
            }
        }
    }
    const int kk = k >> 5, kq = k & 31;
#pragma unroll
    for (int bb = 0; bb < 4; ++bb)
#pragma unroll
        for (int n2 = 0; n2 < 2; ++n2) {
            int b = bs + 16 * bb, n = np * 2 + n2;
            Gpack[(((size_t)b * 16 + kk) * 32 + n) * 32 + kq] = f2bf(acc[bb][n2]);
        }
}

// ---------------------------------------------------------------------------
// routing_mfma: grid 1024 = 64 b x 16 chunks of 64 rows. (R6-verified core.)
// Stage Ab (XOR-swizzled); phase1 logits via 16x16x32 bf16 MFMA; in-register
// softmax; phase2 c^T x Ab via 32x32x16. Epilogue now accumulates directly
// into Ml[b][n][k] fp32 via device-scope atomicAdd (4 MiB, LLC-resident)
// instead of writing 32 MiB of Mp partials. Ml pre-zeroed per iteration.
// ---------------------------------------------------------------------------
__global__ __launch_bounds__(256, 2) void routing_mfma(const u16* __restrict__ Ab,
                                                       const u16* __restrict__ Gpack,
                                                       float* __restrict__ Ml) {
    __shared__ u16 Al[64 * 512];      // 64 KiB
    __shared__ u16 clb[64 * 34];      // 4.25 KiB, c as bf16, stride 34
    const int tid   = threadIdx.x;
    const int lane  = tid & 63;
    const int w     = __builtin_amdgcn_readfirstlane(tid >> 6);
    const int b     = blockIdx.x >> 4;
    const int chunk = blockIdx.x & 15;
    const int row0  = chunk * 64;

    // ---- stage 64 rows, swizzled chunks ----
    const size_t rowbase = (size_t)(b * N_IN + row0);
#pragma unroll
    for (int rr = 0; rr < 16; ++rr) {
        const int r   = w * 16 + rr;
        const int sig = (lane & 56) | ((lane & 7) ^ (r & 7));
        ASYNC_LDS16(Ab + (rowbase + r) * 512 + sig * 8, &Al[r * 512]);
    }
    __syncthreads();

    // ---- phase1: logits[64 r][32 n] via mfma 16x16x32; wave w = m-tile ----
    const int quad = lane >> 4;
    const int l16  = lane & 15;
    f32x4 lacc[2] = {};
    const u16* gb = Gpack + (size_t)b * 16384;
    {
        const int r  = w * 16 + l16;
        const u16* ar = &Al[r * 512];
        for (int kk = 0; kk < 16; ++kk) {
            const int c  = kk * 4 + quad;
            const int cs = (c & 56) | ((c & 7) ^ (r & 7));
            bf16x8 af = *(const bf16x8*)&ar[cs * 8];
#pragma unroll
            for (int nt = 0; nt < 2; ++nt) {
                bf16x8 bf = *(const bf16x8*)&gb[(kk * 32 + nt * 16 + l16) * 32 + quad * 8];
                lacc[nt] = __builtin_amdgcn_mfma_f32_16x16x32_bf16(af, bf, lacc[nt], 0, 0, 0);
            }
        }
    }

    // ---- softmax over the 32 capsules, in-register ----
#pragma unroll
    for (int reg = 0; reg < 4; ++reg) {
        float m = fmaxf(lacc[0][reg], lacc[1][reg]);
        m = fmaxf(m, __shfl_xor(m, 1));
        m = fmaxf(m, __shfl_xor(m, 2));
        m = fmaxf(m, __shfl_xor(m, 4));
        m = fmaxf(m, __shfl_xor(m, 8));
        float e0 = __expf(lacc[0][reg] - m);
        float e1 = __expf(lacc[1][reg] - m);
        float s = e0 + e1;
        s += __shfl_xor(s, 1);
        s += __shfl_xor(s, 2);
        s += __shfl_xor(s, 4);
        s += __shfl_xor(s, 8);
        float inv = 1.f / s;
        const int row = w * 16 + quad * 4 + reg;
        clb[row * 34 + l16]      = f2bf(e0 * inv);
        clb[row * 34 + 16 + l16] = f2bf(e1 * inv);
    }
    __syncthreads();

    // ---- phase2: Ml[32 n][512 k] += c^T x Ab via mfma 32x32x16 ----
    const int h   = lane >> 5;
    const int l32 = lane & 31;
    bf16x8 cfrag[4];
#pragma unroll
    for (int kk2 = 0; kk2 < 4; ++kk2) {
        u16x8 t;
#pragma unroll
        for (int j = 0; j < 8; ++j)
            t[j] = clb[(kk2 * 16 + h * 8 + j) * 34 + l32];
        cfrag[kk2] = __builtin_bit_cast(bf16x8, t);
    }
    float* mlb = Ml + (size_t)b * 32 * 512;
    for (int cti = 0; cti < 4; ++cti) {
        const int ct   = w * 4 + cti;
        const int kcol = ct * 32 + l32;
        const int c2   = kcol >> 3;
        const int e    = kcol & 7;
        f32x16 acc = {};
#pragma unroll
        for (int kk2 = 0; kk2 < 4; ++kk2) {
            u16x8 t;
#pragma unroll
            for (int j = 0; j < 8; ++j) {
                const int r2  = kk2 * 16 + h * 8 + j;
                const int cs2 = (c2 & 56) | ((c2 & 7) ^ (r2 & 7));
                t[j] = Al[r2 * 512 + cs2 * 8 + e];
            }
            bf16x8 bf = __builtin_bit_cast(bf16x8, t);
            acc = __builtin_amdgcn_mfma_f32_32x32x16_bf16(cfrag[kk2], bf, acc, 0, 0, 0);
        }
#pragma unroll
        for (int reg = 0; reg < 16; ++reg) {
            const int n = (reg & 3) + 8 * (reg >> 2) + 4 * h;
            atomicAdd(&mlb[(size_t)n * 512 + kcol], acc[reg]);
        }
    }
}

// ---------------------------------------------------------------------------
// s_final_mfma: s[8b][64d] = Ml x W via mfma_f32_16x16x32_f16 (M=16, rows
// 8..15 zero-pad). Ml read directly (fp32, LLC-resident, 16 KB/block) — the
// 16-chunk Mp gather is gone. B-frag: pre-transposed fp16 W (exact widening
// of bf16 Wb). grid (32 n, 8 bg).
// ---------------------------------------------------------------------------
__global__ __launch_bounds__(256, 1) void s_final_mfma(const float* __restrict__ Ml,
                                                       const u16* __restrict__ Wb,
                                                       float* __restrict__ outs,
                                                       float* __restrict__ outf) {
    __shared__ __align__(16) u16 Wf[32768];     // 64 KiB: [(dtile*16+kk)*4+quad][col16][8]
    __shared__ __align__(16) u16 Mlh[16 * 512]; // 16 KiB fp16, rows 8..15 zero
    __shared__ float Sout[8][64];               // 2 KiB
    const int tid = threadIdx.x;
    const int n   = blockIdx.x;
    const int bg  = blockIdx.y * 8;

    // ---- stage W n-slice into B-fragment layout (bf16 -> fp16, exact) ----
    for (int t = tid; t < 8192; t += 256) {
        int k = t >> 4, d4 = t & 15;
        uint2 raw = *(const uint2*)(Wb + (size_t)k * 2048 + n * 64 + d4 * 4);
        u16 bfv[4] = { (u16)(raw.x & 0xffffu), (u16)(raw.x >> 16),
                       (u16)(raw.y & 0xffffu), (u16)(raw.y >> 16) };
        const int kk = k >> 5, quad = (k >> 3) & 3, j = k & 7;
#pragma unroll
        for (int m = 0; m < 4; ++m) {
            int d = d4 * 4 + m, dtile = d >> 4, col = d & 15;
            Wf[(((dtile * 16 + kk) * 4 + quad) * 16 + col) * 8 + j] = f2h(bf2f(bfv[m]));
        }
    }
    // ---- Ml rows -> fp16 pairs, XOR-swizzled ----
    for (int t = tid; t < 2048; t += 256) {
        int bs = t >> 8, kp = t & 255;
        float2 v = *(const float2*)(Ml + (((size_t)(bg + bs) * 32) + n) * 512 + kp * 2);
        u32 pk = (u32)f2h(v.x) | ((u32)f2h(v.y) << 16);
        ((u32*)Mlh)[(bs * 256 + kp) ^ ((bs & 7) << 2)] = pk;   // byte ^ ((row&7)<<4)
    }
    for (int t = tid; t < 2048; t += 256) ((u32*)Mlh)[2048 + t] = 0;  // pad rows 8..15
    __syncthreads();

    // ---- GEMM: 16 x mfma_f32_16x16x32_f16 per wave (wave = dtile) ----
    const int lane = tid & 63;
    const int w    = tid >> 6;
    const int quad = lane >> 4, l16 = lane & 15;
    f32x4 acc = {};
    for (int kk = 0; kk < 16; ++kk) {
        const int abyte = (l16 * 1024 + kk * 64 + quad * 16) ^ ((l16 & 7) << 4);
        u16x8 a = *(const u16x8*)((const char*)Mlh + abyte);
        u16x8 bfr = *(const u16x8*)&Wf[(((w * 16 + kk) * 4 + quad) * 16 + l16) * 8];
        acc = __builtin_amdgcn_mfma_f32_16x16x32_f16(__builtin_bit_cast(f16x8, a),
                                                     __builtin_bit_cast(f16x8, bfr),
                                                     acc, 0, 0, 0);
    }
    if (quad < 2) {
#pragma unroll
        for (int reg = 0; reg < 4; ++reg)
            Sout[quad * 4 + reg][w * 16 + l16] = acc[reg];
    }
    __syncthreads();

    // ---- squash epilogue ----
    const int w2 = tid >> 6, d = tid & 63;
#pragma unroll
    for (int i = 0; i < 2; ++i) {
        const int row = w2 * 2 + i, b = bg + row;
        float v = Sout[row][d];
        float sq = v * v;
        for (int off = 32; off; off >>= 1) sq += __shfl_xor(sq, off);
        float o = v * (1.0f / sqrtf(sq + 1e-7f));
        size_t idx = (size_t)b * 2048 + n * 64 + d;
        outs[idx] = o;
        if (outf) outf[idx] = o;
    }
}

// ---------------------------------------------------------------------------
extern "C" void kernel_launch(void* const* d_in, const int* in_sizes, int n_in,
                              void* d_out, int out_size, void* d_ws, size_t ws_size,
                              hipStream_t stream) {
    (void)in_sizes; (void)n_in; (void)out_size; (void)ws_size;
    const float* A = (const float*)d_in[0];   // fp32 [65536][512]
    const float* W = (const float*)d_in[1];   // fp32 [512][2048]
    float* out     = (float*)d_out;           // fp32 [64][32][64]

    uint8_t* ws = (uint8_t*)d_ws;
    const size_t AB_B    = (size_t)B_SZ * N_IN * D_IN * 2;          // 64 MiB
    const size_t AROWP_B = (size_t)B_SZ * 32 * D_IN * 4;            // 4 MiB
    const size_t OUTS_B  = (size_t)B_SZ * NC * DC * 4;              // 512 KiB
    const size_t GP_B    = (size_t)B_SZ * 16 * 32 * 32 * 2;         // 2 MiB
    const size_t WB_B    = (size_t)D_IN * NC * DC * 2;              // 2 MiB
    const size_t ML_B    = (size_t)B_SZ * NC * D_IN * 4;            // 4 MiB
    u16*   Ab    = (u16*)ws;
    float* Arowp = (float*)(ws + AB_B);
    float* outs  = (float*)(ws + AB_B + AROWP_B);
    u16*   Gpack = (u16*)(ws + AB_B + AROWP_B + OUTS_B);
    u16*   Wb    = (u16*)(ws + AB_B + AROWP_B + OUTS_B + GP_B);
    float* Ml    = (float*)(ws + AB_B + AROWP_B + OUTS_B + GP_B + WB_B); // 4 MiB fp32

    // prep + iteration-0 input: A->bf16 + row partials, W->bf16 (one kernel)
    conv_all<<<1088, 256, 0, stream>>>(A, W, Ab, Wb, Arowp);

    // iteration 0: uniform c == (1/32) rowsum(A) . W
    s0_squash<<<dim3(8, 32), 256, 0, stream>>>(Arowp, Wb, outs);

    // iterations 1 and 2
    for (int it = 0; it < 2; ++it) {
        hipMemsetAsync(Ml, 0, ML_B, stream);
        g_pack<<<dim3(32, 16), 256, 0, stream>>>(Wb, outs, Gpack);
        routing_mfma<<<1024, 256, 0, stream>>>(Ab, Gpack, Ml);
        s_final_mfma<<<dim3(32, 8), 256, 0, stream>>>(Ml, Wb, outs, it == 1 ? out : nullptr);
    }
}

// Round 7
// 353.337 us; speedup vs baseline: 1.2281x; 1.2281x over previous
//
#include <hip/hip_runtime.h>

// Problem constants
#define B_SZ   64
#define N_IN   1024
#define D_IN   512
#define NC     32
#define DC     64

typedef unsigned short u16;
typedef unsigned int   u32;
typedef __bf16 bf16x8 __attribute__((ext_vector_type(8)));
typedef _Float16 f16x8 __attribute__((ext_vector_type(8)));
typedef unsigned short u16x8 __attribute__((ext_vector_type(8)));
typedef float f32x4  __attribute__((ext_vector_type(4)));
typedef float f32x16 __attribute__((ext_vector_type(16)));

__device__ __forceinline__ float bf2f(u16 u) {
    unsigned x = ((unsigned)u) << 16;
    return __builtin_bit_cast(float, x);
}
__device__ __forceinline__ u16 f2bf(float f) {
    unsigned x = __builtin_bit_cast(unsigned, f);
    unsigned r = (x + 0x7fffu + ((x >> 16) & 1u)) >> 16;   // RNE
    return (u16)r;
}
__device__ __forceinline__ u16 f2h(float f) {             // fp32 -> fp16 bits (RNE)
    return __builtin_bit_cast(u16, (_Float16)f);
}
__device__ __forceinline__ float h2f(u16 h) {
    return (float)__builtin_bit_cast(_Float16, h);
}

#define ASYNC_LDS16(g, l) __builtin_amdgcn_global_load_lds( \
    (const __attribute__((address_space(1))) void*)(g),     \
    (__attribute__((address_space(3))) void*)(l), 16, 0, 0)

// ---------------------------------------------------------------------------
// conv_all: blocks 0..1023 (64 rows each): Ab = bf16(A), Arowp[b][32][512]
// partial row-sums. blocks 1024..1087: Wb = bf16(W).
// ---------------------------------------------------------------------------
__global__ __launch_bounds__(256) void conv_all(const float* __restrict__ A,
                                                const float* __restrict__ W,
                                                u16* __restrict__ Ab,
                                                u16* __restrict__ Wb,
                                                float* __restrict__ Arowp) {
    const int tid = threadIdx.x;
    if (blockIdx.x >= 1024) {                 // W -> bf16, 64 blocks
        const int wb = blockIdx.x - 1024;
#pragma unroll
        for (int it = 0; it < 16; ++it) {
            int i = wb * 4096 + it * 256 + tid;
            float4 v = ((const float4*)W)[i];
            uint2 pk;
            pk.x = (u32)f2bf(v.x) | ((u32)f2bf(v.y) << 16);
            pk.y = (u32)f2bf(v.z) | ((u32)f2bf(v.w) << 16);
            ((uint2*)Wb)[i] = pk;
        }
        return;
    }
    const int b  = blockIdx.x >> 4;
    const int r0 = (blockIdx.x & 15) << 6;    // 64 rows per block
    const int q  = tid & 127;                 // float4 slot within row
    const int rh = tid >> 7;                  // row parity
    const size_t rowbase = (size_t)(b * N_IN + r0);
    float a0 = 0.f, a1 = 0.f, a2 = 0.f, a3 = 0.f;
    for (int r = rh; r < 64; r += 2) {
        float4 v = *(const float4*)(A + (rowbase + r) * 512 + q * 4);
        a0 += v.x; a1 += v.y; a2 += v.z; a3 += v.w;
        uint2 pk;
        pk.x = (u32)f2bf(v.x) | ((u32)f2bf(v.y) << 16);
        pk.y = (u32)f2bf(v.z) | ((u32)f2bf(v.w) << 16);
        *(uint2*)(Ab + (rowbase + r) * 512 + q * 4) = pk;
    }
    const int slot = (blockIdx.x & 15) * 2 + rh;      // 0..31
    float* ar = Arowp + ((size_t)b * 32 + slot) * 512 + q * 4;
    ar[0] = a0; ar[1] = a1; ar[2] = a2; ar[3] = a3;
}

// ---------------------------------------------------------------------------
// s0_squash: s[b][z] = (1/32) Arow[b].Wb[:,z]; squash; -> outs
// grid (8 z-tiles, 32 b-pairs) = 256 blocks.
// ---------------------------------------------------------------------------
__global__ __launch_bounds__(256) void s0_squash(const float* __restrict__ Arowp,
                                                 const u16* __restrict__ Wb,
                                                 float* __restrict__ outs) {
    __shared__ float Al[2 * 512];
    const int tid = threadIdx.x;
    const int z   = blockIdx.x * 256 + tid;
    const int bg  = blockIdx.y * 2;

    for (int t = tid; t < 1024; t += 256) {   // reduce 32 partial slots
        int bb = t >> 9, k = t & 511;
        const float* p = Arowp + ((size_t)(bg + bb) * 32) * 512 + k;
        float s = 0.f;
#pragma unroll
        for (int j = 0; j < 32; ++j) s += p[(size_t)j * 512];
        Al[t] = s;
    }
    __syncthreads();

    float acc[2] = {};
    for (int k = 0; k < 512; ++k) {
        float wv = bf2f(Wb[(size_t)k * 2048 + z]);
        acc[0] += Al[k] * wv;                 // LDS broadcast
        acc[1] += Al[512 + k] * wv;
    }
#pragma unroll
    for (int bb = 0; bb < 2; ++bb) {
        float v = acc[bb] * 0.03125f;
        float sq = v * v;
        for (int off = 32; off; off >>= 1) sq += __shfl_xor(sq, off);
        outs[(size_t)(bg + bb) * 2048 + z] = v * (1.0f / sqrtf(sq + 1e-7f));
    }
}

// ---------------------------------------------------------------------------
// g_pack: Gpack[b][kk][n][kq] = bf16( sum_d Wb[kk*32+kq][n*64+d] * outs[b][n*64+d] )
// grid (32 k-tiles of 16, 16 n-pairs).
// ---------------------------------------------------------------------------
__global__ __launch_bounds__(256) void g_pack(const u16* __restrict__ Wb,
                                              const float* __restrict__ outs,
                                              u16* __restrict__ Gpack) {
    __shared__ float vl[64 * 132];          // [b][2n x 64d], pad->132 (16B align)
    const int tid = threadIdx.x;
    const int kt  = blockIdx.x;
    const int np  = blockIdx.y;

    for (int t = tid; t < 8192; t += 256) {
        int b = t >> 7, idx = t & 127;
        vl[b * 132 + idx] = outs[(size_t)b * 2048 + np * 128 + idx];
    }
    __syncthreads();

    const int bs = tid & 15;
    const int k  = kt * 16 + (tid >> 4);
    float acc[4][2] = {};
#pragma unroll
    for (int n2 = 0; n2 < 2; ++n2) {
        const u16* wr = Wb + (size_t)k * 2048 + (np * 2 + n2) * 64;
#pragma unroll
        for (int d8 = 0; d8 < 8; ++d8) {
            u16x8 w8 = *(const u16x8*)&wr[d8 * 8];     // 16 lanes share addr
            float wf[8];
#pragma unroll
            for (int j = 0; j < 8; ++j) wf[j] = bf2f(w8[j]);
#pragma unroll
            for (int bb = 0; bb < 4; ++bb) {
                const float* vp = &vl[(bs + 16 * bb) * 132 + n2 * 64 + d8 * 8];
                f32x4 va = *(const f32x4*)vp;
                f32x4 vb = *(const f32x4*)(vp + 4);
#pragma unroll
                for (int j = 0; j < 4; ++j) {
                    acc[bb][n2] += wf[j]     * va[j];
                    acc[bb][n2] += wf[j + 4] * vb[j];
                }
            }
        }
    }
    const int kk = k >> 5, kq = k & 31;
#pragma unroll
    for (int bb = 0; bb < 4; ++bb)
#pragma unroll
        for (int n2 = 0; n2 < 2; ++n2) {
            int b = bs + 16 * bb, n = np * 2 + n2;
            Gpack[(((size_t)b * 16 + kk) * 32 + n) * 32 + kq] = f2bf(acc[bb][n2]);
        }
}

// ---------------------------------------------------------------------------
// routing_mfma: grid 256 = 64 b x 4 chunk-groups of 4 chunks (64 rows each).
// Phase2 accumulates across the 4 chunks IN REGISTERS (MFMA C-in/C-out) ->
// Mlp[b][g][32][512] fp16 (8 MiB vs Mp's 32 MiB; no atomics, no memset).
// Double-buffered Al staging: prefetch chunk c+1 issued right after the top
// barrier, overlapping phase1 (the softmax->phase2 barrier drains it).
// LDS 2x64K + clb = 132.25 KiB -> 1 block/CU (within gfx950's 160 KiB).
// Per-chunk math identical to the R6-verified core.
// ---------------------------------------------------------------------------
__global__ __launch_bounds__(256, 1) void routing_mfma(const u16* __restrict__ Ab,
                                                       const u16* __restrict__ Gpack,
                                                       u16* __restrict__ Mlp) {
    __shared__ u16 Al[2][64 * 512];   // 128 KiB, double-buffered
    __shared__ u16 clb[64 * 34];      // 4.25 KiB, c as bf16, stride 34
    const int tid   = threadIdx.x;
    const int lane  = tid & 63;
    const int w     = __builtin_amdgcn_readfirstlane(tid >> 6);
    const int b     = blockIdx.x >> 2;
    const int g     = blockIdx.x & 3;

    const int quad = lane >> 4;
    const int l16  = lane & 15;
    const int h    = lane >> 5;
    const int l32  = lane & 31;
    const u16* gb = Gpack + (size_t)b * 16384;
    const size_t bbase = (size_t)b * N_IN;

    // ---- prologue: stage chunk g*4 into buffer 0 ----
#pragma unroll
    for (int rr = 0; rr < 16; ++rr) {
        const int r   = w * 16 + rr;
        const int sig = (lane & 56) | ((lane & 7) ^ (r & 7));
        ASYNC_LDS16(Ab + (bbase + (size_t)(g * 4) * 64 + r) * 512 + sig * 8,
                    &Al[0][r * 512]);
    }

    f32x16 acc4[4] = {};              // persistent accumulator (4 cti x 16)

    for (int cc = 0; cc < 4; ++cc) {
        const int buf = cc & 1;
        __syncthreads();              // buf staged; prev phase2 done; clb free

        if (cc < 3) {                 // prefetch next chunk into buf^1
#pragma unroll
            for (int rr = 0; rr < 16; ++rr) {
                const int r   = w * 16 + rr;
                const int sig = (lane & 56) | ((lane & 7) ^ (r & 7));
                ASYNC_LDS16(Ab + (bbase + (size_t)(g * 4 + cc + 1) * 64 + r) * 512 + sig * 8,
                            &Al[buf ^ 1][r * 512]);
            }
        }

        // ---- phase1: logits[64 r][32 n] via mfma 16x16x32 ----
        f32x4 lacc[2] = {};
        {
            const int r  = w * 16 + l16;
            const u16* ar = &Al[buf][r * 512];
            for (int kk = 0; kk < 16; ++kk) {
                const int c  = kk * 4 + quad;
                const int cs = (c & 56) | ((c & 7) ^ (r & 7));
                bf16x8 af = *(const bf16x8*)&ar[cs * 8];
#pragma unroll
                for (int nt = 0; nt < 2; ++nt) {
                    bf16x8 bf = *(const bf16x8*)&gb[(kk * 32 + nt * 16 + l16) * 32 + quad * 8];
                    lacc[nt] = __builtin_amdgcn_mfma_f32_16x16x32_bf16(af, bf, lacc[nt], 0, 0, 0);
                }
            }
        }

        // ---- softmax over the 32 capsules, in-register ----
#pragma unroll
        for (int reg = 0; reg < 4; ++reg) {
            float m = fmaxf(lacc[0][reg], lacc[1][reg]);
            m = fmaxf(m, __shfl_xor(m, 1));
            m = fmaxf(m, __shfl_xor(m, 2));
            m = fmaxf(m, __shfl_xor(m, 4));
            m = fmaxf(m, __shfl_xor(m, 8));
            float e0 = __expf(lacc[0][reg] - m);
            float e1 = __expf(lacc[1][reg] - m);
            float s = e0 + e1;
            s += __shfl_xor(s, 1);
            s += __shfl_xor(s, 2);
            s += __shfl_xor(s, 4);
            s += __shfl_xor(s, 8);
            float inv = 1.f / s;
            const int row = w * 16 + quad * 4 + reg;
            clb[row * 34 + l16]      = f2bf(e0 * inv);
            clb[row * 34 + 16 + l16] = f2bf(e1 * inv);
        }
        __syncthreads();

        // ---- phase2: acc4 += c^T x Ab via mfma 32x32x16 ----
        bf16x8 cfrag[4];
#pragma unroll
        for (int kk2 = 0; kk2 < 4; ++kk2) {
            u16x8 t;
#pragma unroll
            for (int j = 0; j < 8; ++j)
                t[j] = clb[(kk2 * 16 + h * 8 + j) * 34 + l32];
            cfrag[kk2] = __builtin_bit_cast(bf16x8, t);
        }
#pragma unroll
        for (int cti = 0; cti < 4; ++cti) {
            const int ct   = w * 4 + cti;
            const int kcol = ct * 32 + l32;
            const int c2   = kcol >> 3;
            const int e    = kcol & 7;
#pragma unroll
            for (int kk2 = 0; kk2 < 4; ++kk2) {
                u16x8 t;
#pragma unroll
                for (int j = 0; j < 8; ++j) {
                    const int r2  = kk2 * 16 + h * 8 + j;
                    const int cs2 = (c2 & 56) | ((c2 & 7) ^ (r2 & 7));
                    t[j] = Al[buf][r2 * 512 + cs2 * 8 + e];
                }
                bf16x8 bf = __builtin_bit_cast(bf16x8, t);
                acc4[cti] = __builtin_amdgcn_mfma_f32_32x32x16_bf16(cfrag[kk2], bf, acc4[cti], 0, 0, 0);
            }
        }
    }

    // ---- epilogue: one fp16 write of the 4-chunk partial ----
    u16* mpb = Mlp + (((size_t)b * 4 + g) * 32) * 512;
#pragma unroll
    for (int cti = 0; cti < 4; ++cti) {
        const int kcol = (w * 4 + cti) * 32 + l32;
#pragma unroll
        for (int reg = 0; reg < 16; ++reg) {
            const int n = (reg & 3) + 8 * (reg >> 2) + 4 * h;
            mpb[(size_t)n * 512 + kcol] = f2h(acc4[cti][reg]);
        }
    }
}

// ---------------------------------------------------------------------------
// s_final_mfma: Ml[b][k] = sum_g Mlp (4 fp16 slots); s[8b][64d] = Ml x W via
// mfma_f32_16x16x32_f16 (M=16, rows 8..15 zero-pad). grid (32 n, 8 bg).
// ---------------------------------------------------------------------------
__global__ __launch_bounds__(256, 1) void s_final_mfma(const u16* __restrict__ Mlp,
                                                       const u16* __restrict__ Wb,
                                                       float* __restrict__ outs,
                                                       float* __restrict__ outf) {
    __shared__ __align__(16) u16 Wf[32768];     // 64 KiB: [(dtile*16+kk)*4+quad][col16][8]
    __shared__ __align__(16) u16 Mlh[16 * 512]; // 16 KiB fp16, rows 8..15 zero
    __shared__ float Sout[8][64];               // 2 KiB
    const int tid = threadIdx.x;
    const int n   = blockIdx.x;
    const int bg  = blockIdx.y * 8;

    // ---- stage W n-slice into B-fragment layout (bf16 -> fp16, exact) ----
    for (int t = tid; t < 8192; t += 256) {
        int k = t >> 4, d4 = t & 15;
        uint2 raw = *(const uint2*)(Wb + (size_t)k * 2048 + n * 64 + d4 * 4);
        u16 bfv[4] = { (u16)(raw.x & 0xffffu), (u16)(raw.x >> 16),
                       (u16)(raw.y & 0xffffu), (u16)(raw.y >> 16) };
        const int kk = k >> 5, quad = (k >> 3) & 3, j = k & 7;
#pragma unroll
        for (int m = 0; m < 4; ++m) {
            int d = d4 * 4 + m, dtile = d >> 4, col = d & 15;
            Wf[(((dtile * 16 + kk) * 4 + quad) * 16 + col) * 8 + j] = f2h(bf2f(bfv[m]));
        }
    }
    // ---- Ml rows: 4-slot fp16 reduce -> fp16 pairs, XOR-swizzled ----
    for (int t = tid; t < 2048; t += 256) {
        int bs = t >> 8, kp = t & 255;
        const u32* p = (const u32*)Mlp + (((size_t)(bg + bs) * 4) * 32 + n) * 256 + kp;
        float s0 = 0.f, s1 = 0.f;
#pragma unroll
        for (int gg = 0; gg < 4; ++gg) {
            u32 v = p[(size_t)gg * 32 * 256];
            s0 += h2f((u16)(v & 0xffffu));
            s1 += h2f((u16)(v >> 16));
        }
        u32 pk = (u32)f2h(s0) | ((u32)f2h(s1) << 16);
        ((u32*)Mlh)[(bs * 256 + kp) ^ ((bs & 7) << 2)] = pk;   // byte ^ ((row&7)<<4)
    }
    for (int t = tid; t < 2048; t += 256) ((u32*)Mlh)[2048 + t] = 0;  // pad rows 8..15
    __syncthreads();

    // ---- GEMM: 16 x mfma_f32_16x16x32_f16 per wave (wave = dtile) ----
    const int lane = tid & 63;
    const int w    = tid >> 6;
    const int quad = lane >> 4, l16 = lane & 15;
    f32x4 acc = {};
    for (int kk = 0; kk < 16; ++kk) {
        const int abyte = (l16 * 1024 + kk * 64 + quad * 16) ^ ((l16 & 7) << 4);
        u16x8 a = *(const u16x8*)((const char*)Mlh + abyte);
        u16x8 bfr = *(const u16x8*)&Wf[(((w * 16 + kk) * 4 + quad) * 16 + l16) * 8];
        acc = __builtin_amdgcn_mfma_f32_16x16x32_f16(__builtin_bit_cast(f16x8, a),
                                                     __builtin_bit_cast(f16x8, bfr),
                                                     acc, 0, 0, 0);
    }
    if (quad < 2) {
#pragma unroll
        for (int reg = 0; reg < 4; ++reg)
            Sout[quad * 4 + reg][w * 16 + l16] = acc[reg];
    }
    __syncthreads();

    // ---- squash epilogue ----
    const int w2 = tid >> 6, d = tid & 63;
#pragma unroll
    for (int i = 0; i < 2; ++i) {
        const int row = w2 * 2 + i, b = bg + row;
        float v = Sout[row][d];
        float sq = v * v;
        for (int off = 32; off; off >>= 1) sq += __shfl_xor(sq, off);
        float o = v * (1.0f / sqrtf(sq + 1e-7f));
        size_t idx = (size_t)b * 2048 + n * 64 + d;
        outs[idx] = o;
        if (outf) outf[idx] = o;
    }
}

// ---------------------------------------------------------------------------
extern "C" void kernel_launch(void* const* d_in, const int* in_sizes, int n_in,
                              void* d_out, int out_size, void* d_ws, size_t ws_size,
                              hipStream_t stream) {
    (void)in_sizes; (void)n_in; (void)out_size; (void)ws_size;
    const float* A = (const float*)d_in[0];   // fp32 [65536][512]
    const float* W = (const float*)d_in[1];   // fp32 [512][2048]
    float* out     = (float*)d_out;           // fp32 [64][32][64]

    uint8_t* ws = (uint8_t*)d_ws;
    const size_t AB_B    = (size_t)B_SZ * N_IN * D_IN * 2;          // 64 MiB
    const size_t AROWP_B = (size_t)B_SZ * 32 * D_IN * 4;            // 4 MiB
    const size_t OUTS_B  = (size_t)B_SZ * NC * DC * 4;              // 512 KiB
    const size_t GP_B    = (size_t)B_SZ * 16 * 32 * 32 * 2;         // 2 MiB
    const size_t WB_B    = (size_t)D_IN * NC * DC * 2;              // 2 MiB
    u16*   Ab    = (u16*)ws;
    float* Arowp = (float*)(ws + AB_B);
    float* outs  = (float*)(ws + AB_B + AROWP_B);
    u16*   Gpack = (u16*)(ws + AB_B + AROWP_B + OUTS_B);
    u16*   Wb    = (u16*)(ws + AB_B + AROWP_B + OUTS_B + GP_B);
    u16*   Mlp   = (u16*)(ws + AB_B + AROWP_B + OUTS_B + GP_B + WB_B); // 8 MiB fp16

    // prep + iteration-0 input: A->bf16 + row partials, W->bf16 (one kernel)
    conv_all<<<1088, 256, 0, stream>>>(A, W, Ab, Wb, Arowp);

    // iteration 0: uniform c == (1/32) rowsum(A) . W
    s0_squash<<<dim3(8, 32), 256, 0, stream>>>(Arowp, Wb, outs);

    // iterations 1 and 2
    for (int it = 0; it < 2; ++it) {
        g_pack<<<dim3(32, 16), 256, 0, stream>>>(Wb, outs, Gpack);
        routing_mfma<<<256, 256, 0, stream>>>(Ab, Gpack, Mlp);
        s_final_mfma<<<dim3(32, 8), 256, 0, stream>>>(Mlp, Wb, outs, it == 1 ? out : nullptr);
    }
}